// Round 1
// baseline (313.575 us; speedup 1.0000x reference)
//
#include <hip/hip_runtime.h>

#define INV_SQRT2f 0.70710678118654752440f

// Analysis filters; synthesis filter f[k] = AF[9-k] (time reversal).
// Polyphase synthesis: out[2q+p] = sum_{j=0..4} AF[9-(2j+p)] * x[(q+2-j) mod Nin]
__constant__ float c_FAR[2][2][10] = {
  {{0.0f, -0.08838834764832f, 0.08838834764832f, 0.69587998903400f, 0.69587998903400f,
    0.08838834764832f, -0.08838834764832f, 0.01122679215254f, 0.01122679215254f, 0.0f},
   {0.0f, -0.01122679215254f, 0.01122679215254f, 0.08838834764832f, 0.08838834764832f,
    -0.69587998903400f, 0.69587998903400f, -0.08838834764832f, -0.08838834764832f, 0.0f}},
  {{0.01122679215254f, 0.01122679215254f, -0.08838834764832f, 0.08838834764832f, 0.69587998903400f,
    0.69587998903400f, 0.08838834764832f, -0.08838834764832f, 0.0f, 0.0f},
   {0.0f, 0.0f, -0.08838834764832f, -0.08838834764832f, 0.69587998903400f,
    -0.69587998903400f, 0.08838834764832f, 0.08838834764832f, 0.01122679215254f, -0.01122679215254f}}
};
__constant__ float c_DUAL[2][2][10] = {
  {{0.03516384f, 0.0f, -0.08832942f, 0.23389032f, 0.76027237f,
    0.58751830f, 0.0f, -0.11430184f, 0.0f, 0.0f},
   {0.0f, 0.0f, -0.11430184f, 0.0f, 0.58751830f,
    -0.76027237f, 0.23389032f, 0.08832942f, 0.0f, -0.03516384f}},
  {{0.0f, 0.0f, -0.11430184f, 0.0f, 0.58751830f,
    0.76027237f, 0.23389032f, -0.08832942f, 0.0f, 0.03516384f},
   {-0.03516384f, 0.0f, 0.08832942f, 0.23389032f, -0.76027237f,
    0.58751830f, 0.0f, -0.11430184f, 0.0f, 0.0f}}
};

// ---------------- Stage A: q-shift level (128 -> 256), writes mid[q][b][256][256][16]
// tile: 8x8 input -> 16x16 output, all 16 channels, 256 threads.
__global__ __launch_bounds__(256) void qshift_kernel(
    const float* __restrict__ w2, const float* __restrict__ loT, float* __restrict__ mid)
{
  __shared__ float sIn[4][12][12][16];   // lo, LH, HL, HH (input tiles + halo 2)
  __shared__ float sMid[2][12][16][16];  // col-pass intermediates: lo', h'

  const int tid = threadIdx.x;
  const int c = tid & 15;
  const int s = tid >> 4;           // 0..15
  const int tw = blockIdx.x;        // 0..15
  const int th = blockIdx.y;        // 0..15
  const int b  = blockIdx.z & 3;
  const int q  = blockIdx.z >> 2;   // quadrant 0..3
  const int m = q >> 1, n = q & 1;
  const int j1 = m ^ n;
  const float sgn = m ? -1.0f : 1.0f;
  const int ih0 = th * 8, iw0 = tw * 8;

  const size_t plane = (size_t)128 * 128 * 16;
  const float* loQ = loT + ((size_t)(m * 2 + n) * 4 + b) * plane;
  const float* wA0 = w2 + ((size_t)((0 * 2 + j1) * 3 + 0) * 4 + b) * plane;
  const float* wA1 = w2 + ((size_t)((0 * 2 + j1) * 3 + 1) * 4 + b) * plane;
  const float* wA2 = w2 + ((size_t)((0 * 2 + j1) * 3 + 2) * 4 + b) * plane;
  const float* wB0 = w2 + ((size_t)((1 * 2 + (1 ^ j1)) * 3 + 0) * 4 + b) * plane;
  const float* wB1 = w2 + ((size_t)((1 * 2 + (1 ^ j1)) * 3 + 1) * 4 + b) * plane;
  const float* wB2 = w2 + ((size_t)((1 * 2 + (1 ^ j1)) * 3 + 2) * 4 + b) * plane;

  // Phase A: stage inputs (12x12 spatial halo tile, 16 ch), mixing w2 on the fly
  #pragma unroll
  for (int it = 0; it < 9; ++it) {
    int e = s + 16 * it;            // 0..143
    int r = e / 12, col = e % 12;
    int gr = (ih0 + r - 2) & 127;
    int gc = (iw0 + col - 2) & 127;
    size_t sp = ((size_t)gr * 128 + gc) * 16 + c;
    sIn[0][r][col][c] = loQ[sp];
    sIn[1][r][col][c] = (wA0[sp] + sgn * wB0[sp]) * INV_SQRT2f;
    sIn[2][r][col][c] = (wA1[sp] + sgn * wB1[sp]) * INV_SQRT2f;
    sIn[3][r][col][c] = (wA2[sp] + sgn * wB2[sp]) * INV_SQRT2f;
  }
  __syncthreads();

  // Phase B: column pass (along W), tree n filters. Each thread owns out-col nw=s.
  {
    const int nw = s, pw = nw & 1, qw = nw >> 1;
    float flp[5], fhp[5];
    #pragma unroll
    for (int j = 0; j < 5; ++j) {
      flp[j] = c_DUAL[n][0][9 - (2 * j + pw)];
      fhp[j] = c_DUAL[n][1][9 - (2 * j + pw)];
    }
    #pragma unroll
    for (int r = 0; r < 12; ++r) {
      float lo_v = 0.f, h_v = 0.f;
      #pragma unroll
      for (int j = 0; j < 5; ++j) {
        int x = qw + 4 - j;
        lo_v += flp[j] * sIn[0][r][x][c] + fhp[j] * sIn[1][r][x][c];
        h_v  += flp[j] * sIn[2][r][x][c] + fhp[j] * sIn[3][r][x][c];
      }
      sMid[0][r][nw][c] = lo_v;
      sMid[1][r][nw][c] = h_v;
    }
  }
  __syncthreads();

  // Phase C: row pass (along H), tree m filters; write mid.
  float* outQ = mid + ((size_t)q * 4 + b) * (size_t)(256 * 256 * 16);
  {
    const int nw = s;
    #pragma unroll
    for (int nh = 0; nh < 16; ++nh) {
      int ph = nh & 1, qh = nh >> 1;
      float v = 0.f;
      #pragma unroll
      for (int j = 0; j < 5; ++j) {
        float flp = c_DUAL[m][0][9 - (2 * j + ph)];
        float fhp = c_DUAL[m][1][9 - (2 * j + ph)];
        int r = qh + 4 - j;
        v += flp * sMid[0][r][nw][c] + fhp * sMid[1][r][nw][c];
      }
      outQ[(((size_t)(ih0 * 2 + nh)) * 256 + (size_t)(iw0 * 2 + nw)) * 16 + c] = v;
    }
  }
}

// ---------------- Stage B: Farras level (256 -> 512), sums 4 quadrants, writes out*0.5
__global__ __launch_bounds__(256) void farras_kernel(
    const float* __restrict__ w1, const float* __restrict__ mid, float* __restrict__ out)
{
  __shared__ float sIn[4][12][12][16];
  __shared__ float sMid[2][12][16][16];

  const int tid = threadIdx.x;
  const int c = tid & 15;
  const int s = tid >> 4;
  const int tw = blockIdx.x;        // 0..31
  const int th = blockIdx.y;        // 0..31
  const int b  = blockIdx.z;        // 0..3
  const int ih0 = th * 8, iw0 = tw * 8;
  const size_t plane = (size_t)256 * 256 * 16;

  float acc[16];
  #pragma unroll
  for (int i = 0; i < 16; ++i) acc[i] = 0.f;

  for (int q = 0; q < 4; ++q) {
    const int m = q >> 1, n = q & 1;
    const int j1 = m ^ n;
    const float sgn = m ? -1.0f : 1.0f;
    const float* midQ = mid + ((size_t)q * 4 + b) * plane;
    const float* wA0 = w1 + ((size_t)((0 * 2 + j1) * 3 + 0) * 4 + b) * plane;
    const float* wA1 = w1 + ((size_t)((0 * 2 + j1) * 3 + 1) * 4 + b) * plane;
    const float* wA2 = w1 + ((size_t)((0 * 2 + j1) * 3 + 2) * 4 + b) * plane;
    const float* wB0 = w1 + ((size_t)((1 * 2 + (1 ^ j1)) * 3 + 0) * 4 + b) * plane;
    const float* wB1 = w1 + ((size_t)((1 * 2 + (1 ^ j1)) * 3 + 1) * 4 + b) * plane;
    const float* wB2 = w1 + ((size_t)((1 * 2 + (1 ^ j1)) * 3 + 2) * 4 + b) * plane;

    // Phase A (safe vs. prev iter's Phase C: disjoint LDS arrays)
    #pragma unroll
    for (int it = 0; it < 9; ++it) {
      int e = s + 16 * it;
      int r = e / 12, col = e % 12;
      int gr = (ih0 + r - 2) & 255;
      int gc = (iw0 + col - 2) & 255;
      size_t sp = ((size_t)gr * 256 + gc) * 16 + c;
      sIn[0][r][col][c] = midQ[sp];
      sIn[1][r][col][c] = (wA0[sp] + sgn * wB0[sp]) * INV_SQRT2f;
      sIn[2][r][col][c] = (wA1[sp] + sgn * wB1[sp]) * INV_SQRT2f;
      sIn[3][r][col][c] = (wA2[sp] + sgn * wB2[sp]) * INV_SQRT2f;
    }
    __syncthreads();

    // Phase B: column pass, tree n
    {
      const int nw = s, pw = nw & 1, qw = nw >> 1;
      float flp[5], fhp[5];
      #pragma unroll
      for (int j = 0; j < 5; ++j) {
        flp[j] = c_FAR[n][0][9 - (2 * j + pw)];
        fhp[j] = c_FAR[n][1][9 - (2 * j + pw)];
      }
      #pragma unroll
      for (int r = 0; r < 12; ++r) {
        float lo_v = 0.f, h_v = 0.f;
        #pragma unroll
        for (int j = 0; j < 5; ++j) {
          int x = qw + 4 - j;
          lo_v += flp[j] * sIn[0][r][x][c] + fhp[j] * sIn[1][r][x][c];
          h_v  += flp[j] * sIn[2][r][x][c] + fhp[j] * sIn[3][r][x][c];
        }
        sMid[0][r][nw][c] = lo_v;
        sMid[1][r][nw][c] = h_v;
      }
    }
    __syncthreads();

    // Phase C: row pass, tree m; accumulate into registers
    {
      const int nw = s;
      #pragma unroll
      for (int nh = 0; nh < 16; ++nh) {
        int ph = nh & 1, qh = nh >> 1;
        float v = 0.f;
        #pragma unroll
        for (int j = 0; j < 5; ++j) {
          float flp = c_FAR[m][0][9 - (2 * j + ph)];
          float fhp = c_FAR[m][1][9 - (2 * j + ph)];
          int r = qh + 4 - j;
          v += flp * sMid[0][r][nw][c] + fhp * sMid[1][r][nw][c];
        }
        acc[nh] += v;
      }
    }
    __syncthreads();  // protect sIn/sMid before next quadrant overwrites
  }

  // Write output [B,512,512,16] * 0.5
  {
    const int nw = s;
    #pragma unroll
    for (int nh = 0; nh < 16; ++nh) {
      size_t gh = (size_t)(ih0 * 2 + nh);
      size_t gw = (size_t)(iw0 * 2 + nw);
      out[(((size_t)b * 512 + gh) * 512 + gw) * 16 + c] = acc[nh] * 0.5f;
    }
  }
}

extern "C" void kernel_launch(void* const* d_in, const int* in_sizes, int n_in,
                              void* d_out, int out_size, void* d_ws, size_t ws_size,
                              hipStream_t stream) {
  const float* w1 = (const float*)d_in[0];   // [2,2,3,4,256,256,16]
  const float* w2 = (const float*)d_in[1];   // [2,2,3,4,128,128,16]
  const float* lo = (const float*)d_in[2];   // [2,2,4,128,128,16]
  float* out = (float*)d_out;                // [4,512,512,16]
  float* mid = (float*)d_ws;                 // [4 quadrants][4][256][256][16] = 64 MiB

  // Stage A: q-shift synthesis per quadrant -> mid
  qshift_kernel<<<dim3(16, 16, 16), 256, 0, stream>>>(w2, lo, mid);
  // Stage B: Farras synthesis, sum quadrants -> out
  farras_kernel<<<dim3(32, 32, 4), 256, 0, stream>>>(w1, mid, out);
}